// Round 7
// baseline (284.127 us; speedup 1.0000x reference)
//
#include <hip/hip_runtime.h>
#include <hip/hip_cooperative_groups.h>
#include <stdint.h>
#include <stddef.h>

namespace cg = cooperative_groups;

#define N_SENT 100000
#define N_TYPE 10000
#define NEDGE  640000
#define NROWS  (N_SENT + N_TYPE)
#define MAXDEG 256    // LDS cache per wave in agg_k; Poisson(64): P(deg>256) ~ 0. Fallback exists.
#define HB     256    // histogram chunks; 256 * 2500 == NEDGE exactly
#define HCHUNK (NEDGE / HB)   // 2500

__device__ __forceinline__ float bf2f(uint32_t lo16) {
    return __builtin_bit_cast(float, lo16 << 16);
}
__device__ __forceinline__ uint32_t f2bf(float f) {
    uint32_t u = __builtin_bit_cast(uint32_t, f);
    return (u + 0x7fffu + ((u >> 16) & 1u)) >> 16;
}

// Inline per-wave dtype probe: bf16 pairs have bf16-sane exponents in the low halfword;
// f32 low halfwords are mantissa bits (uniform). One broadcast load + ballot, wave-uniform.
__device__ __forceinline__ bool detect_bf16(const uint32_t* __restrict__ h) {
    uint32_t u = h[threadIdx.x & 63];
    uint32_t e_lo = (u >> 7) & 0xffu;
    int ok = (e_lo >= 100u && e_lo <= 140u) ? 1 : 0;
    unsigned long long m = __ballot(ok);
    return __popcll(m) >= 48;
}

// ---- scores: streaming matvec (round-5 version, verified) ----
#define SC_BLOCKS 6875   // 6875*256 = 1,760,000 = NROWS*16 (bf16 chunks) = (NROWS*32)/2 (f32)

__global__ __launch_bounds__(256) void scores_k(const void* __restrict__ h_sent,
                                                const void* __restrict__ h_type,
                                                const void* __restrict__ attn_w,
                                                float* __restrict__ s_src,
                                                float* __restrict__ s_dst) {
    int t    = blockIdx.x * 256 + (int)threadIdx.x;
    int lane = threadIdx.x & 63;
    bool isbf = detect_bf16((const uint32_t*)h_sent);
    if (isbf) {
        uint4 wsv = ((const uint4*)attn_w)[lane & 15];        // 8 bf16 dims of w[:D]
        uint4 wtv = ((const uint4*)attn_w)[16 + (lane & 15)]; // 8 bf16 dims of w[D:]
        bool isSrc = t < N_SENT * 16;
        const uint4* p = isSrc ? (const uint4*)h_sent + t
                               : (const uint4*)h_type + (t - N_SENT * 16);
        uint4 h = *p;
        uint4 wv = isSrc ? wsv : wtv;
        float s = bf2f(h.x & 0xffffu) * bf2f(wv.x & 0xffffu)
                + bf2f(h.x >> 16)     * bf2f(wv.x >> 16)
                + bf2f(h.y & 0xffffu) * bf2f(wv.y & 0xffffu)
                + bf2f(h.y >> 16)     * bf2f(wv.y >> 16)
                + bf2f(h.z & 0xffffu) * bf2f(wv.z & 0xffffu)
                + bf2f(h.z >> 16)     * bf2f(wv.z >> 16)
                + bf2f(h.w & 0xffffu) * bf2f(wv.w & 0xffffu)
                + bf2f(h.w >> 16)     * bf2f(wv.w >> 16);
        s += __shfl_xor(s, 1, 64);
        s += __shfl_xor(s, 2, 64);
        s += __shfl_xor(s, 4, 64);
        s += __shfl_xor(s, 8, 64);
        if ((lane & 15) == 0) {
            int row = t >> 4;
            if (row < N_SENT) s_src[row] = s;
            else              s_dst[row - N_SENT] = s;
        }
    } else {
        float4 wsv = ((const float4*)attn_w)[lane & 31];        // 4 f32 dims of w[:D]
        float4 wtv = ((const float4*)attn_w)[32 + (lane & 31)]; // 4 f32 dims of w[D:]
        const int HALF = NROWS * 16;   // items total = NROWS*32
        int it0 = t, it1 = t + HALF;   // both ≡ lane (mod 32)
        bool s0 = it0 < N_SENT * 32, s1 = it1 < N_SENT * 32;
        const float4* p0 = s0 ? (const float4*)h_sent + it0
                              : (const float4*)h_type + (it0 - N_SENT * 32);
        const float4* p1 = s1 ? (const float4*)h_sent + it1
                              : (const float4*)h_type + (it1 - N_SENT * 32);
        float4 h0 = *p0;
        float4 h1 = *p1;
        __builtin_amdgcn_sched_barrier(0);   // both loads in flight
        float4 w0 = s0 ? wsv : wtv, w1 = s1 ? wsv : wtv;
        float a = h0.x * w0.x + h0.y * w0.y + h0.z * w0.z + h0.w * w0.w;
        float b = h1.x * w1.x + h1.y * w1.y + h1.z * w1.z + h1.w * w1.w;
        a += __shfl_xor(a, 1, 64);  b += __shfl_xor(b, 1, 64);
        a += __shfl_xor(a, 2, 64);  b += __shfl_xor(b, 2, 64);
        a += __shfl_xor(a, 4, 64);  b += __shfl_xor(b, 4, 64);
        a += __shfl_xor(a, 8, 64);  b += __shfl_xor(b, 8, 64);
        a += __shfl_xor(a, 16, 64); b += __shfl_xor(b, 16, 64);
        if ((lane & 31) == 0) {
            int r0 = it0 >> 5, r1 = it1 >> 5;
            if (r0 < N_SENT) s_src[r0] = a; else s_dst[r0 - N_SENT] = a;
            if (r1 < N_SENT) s_src[r1] = b; else s_dst[r1 - N_SENT] = b;
        }
    }
}

// ==== coop CSR-build: count -> column-scan -> offsets-scan -> fill ====
// EXACTLY 256 blocks (1 block/CU at 40KB LDS; 4x occupancy margin so the coop
// co-residency validation cannot fail — round-6's BB=1024 was an exact fit and
// the launch was rejected, leaving agg to run on a garbage workspace).
__global__ __launch_bounds__(256) void build2_k(const int* __restrict__ src,
                                                const int* __restrict__ dst,
                                                uint32_t* __restrict__ count2,
                                                uint32_t* __restrict__ total,
                                                uint32_t* __restrict__ offsets,
                                                uint32_t* __restrict__ edge_src) {
    __shared__ uint32_t hist[N_TYPE];   // 40 KB: hist (count) -> scratch (O) -> cur (fill)
    cg::grid_group gg = cg::this_grid();
    int bid  = blockIdx.x;              // [0, 256)
    int t    = threadIdx.x;
    int lane = t & 63;
    int tid  = bid * 256 + t;

    // ---- phase C: per-chunk LDS histogram -> count2[bid][bin] ----
    {
#pragma unroll
        for (int i = 0; i < 40; i++) {      // 40*256 >= N_TYPE
            int idx = i * 256 + t;
            if (idx < N_TYPE) hist[idx] = 0u;
        }
        __syncthreads();
        int e0 = bid * HCHUNK;
        int dv[10];                          // HCHUNK = 2500 <= 10*256
#pragma unroll
        for (int k = 0; k < 10; k++) {
            int i = k * 256 + t;
            dv[k] = dst[e0 + (i < HCHUNK ? i : HCHUNK - 1)];
        }
        __builtin_amdgcn_sched_barrier(0);   // all 10 loads in flight
#pragma unroll
        for (int k = 0; k < 10; k++) {
            int i = k * 256 + t;
            if (i < HCHUNK) atomicAdd(&hist[dv[k]], 1u);
        }
        __syncthreads();
        uint4* row = (uint4*)(count2 + (size_t)bid * N_TYPE);
#pragma unroll
        for (int i = 0; i < 10; i++) {       // 2500 uint4 = 10000 words
            int idx = i * 256 + t;
            if (idx < N_TYPE / 4) row[idx] = ((const uint4*)hist)[idx];
        }
    }
    gg.sync();

    // ---- phase P: column exclusive-scan over 256 chunks; 4-lane group per bin ----
    {
        int grp = tid >> 2;                  // bin
        int sub = t & 3;                     // chunk sub-range [sub*64, sub*64+64)
        if (grp < N_TYPE) {
            uint32_t vals[64];
#pragma unroll
            for (int c = 0; c < 64; c++)     // 64 independent loads
                vals[c] = count2[(size_t)(sub * 64 + c) * N_TYPE + grp];
            __builtin_amdgcn_sched_barrier(0);
            uint32_t lsum = 0;
#pragma unroll
            for (int c = 0; c < 64; c++) lsum += vals[c];
            // segmented inclusive scan over the 4 subs (segments of 4 lanes)
            uint32_t incl = lsum;
#pragma unroll
            for (int off = 1; off < 4; off <<= 1) {
                uint32_t v = __shfl_up(incl, off, 64);
                if ((lane & 3) >= off) incl += v;
            }
            uint32_t run = incl - lsum;      // exclusive base for this sub-range
#pragma unroll
            for (int c = 0; c < 64; c++) {
                uint32_t v = vals[c];
                count2[(size_t)(sub * 64 + c) * N_TYPE + grp] = run;
                run += v;
            }
            if (sub == 3) total[grp] = incl; // full column sum
        }
    }
    gg.sync();

    // ---- phase O: exclusive scan of totals -> offsets[N_TYPE+1] (block 0 only) ----
    if (bid == 0) {
        const int CH = 40;                   // 256*40 >= N_TYPE+1
        int wv = t >> 6;                     // 4 waves
        int base = t * CH;
        uint32_t local[CH];
        uint32_t tsum = 0;
#pragma unroll
        for (int i = 0; i < CH; i++) {
            int idx = base + i;
            uint32_t c = (idx < N_TYPE) ? total[idx] : 0u;
            local[i] = c;
            tsum += c;
        }
        uint32_t incl = tsum;
#pragma unroll
        for (int off = 1; off < 64; off <<= 1) {
            uint32_t v = __shfl_up(incl, off, 64);
            if (lane >= off) incl += v;
        }
        if (lane == 63) hist[wv] = incl;     // reuse LDS for wave sums
        __syncthreads();
        uint32_t wbase = 0;
#pragma unroll
        for (int w = 0; w < 4; w++) wbase += (w < wv) ? hist[w] : 0u;
        uint32_t run = wbase + incl - tsum;  // exclusive thread prefix
#pragma unroll
        for (int i = 0; i < CH; i++) {
            int idx = base + i;
            if (idx < N_TYPE) {
                offsets[idx] = run;
                run += local[i];
            } else if (idx == N_TYPE) {
                offsets[idx] = run;          // == NEDGE
            }
        }
    }
    gg.sync();

    // ---- phase F: fill edge_src; LDS cursors = offsets + column base ----
    {
        const uint32_t* brow = count2 + (size_t)bid * N_TYPE;
#pragma unroll
        for (int i = 0; i < 10; i++) {       // 2500 uint4 covers 10000 bins
            int idx = i * 256 + t;
            if (idx < N_TYPE / 4) {
                uint4 o = ((const uint4*)offsets)[idx];
                uint4 b = ((const uint4*)brow)[idx];
                uint4 c; c.x = o.x + b.x; c.y = o.y + b.y; c.z = o.z + b.z; c.w = o.w + b.w;
                ((uint4*)hist)[idx] = c;     // hist reused as cursor array
            }
        }
        __syncthreads();
        int e0 = bid * HCHUNK;
        int dv[10], sv[10];
#pragma unroll
        for (int k = 0; k < 10; k++) {       // all 20 loads upfront
            int i = k * 256 + t;
            int e = e0 + (i < HCHUNK ? i : HCHUNK - 1);
            dv[k] = dst[e];
            sv[k] = src[e];
        }
        __builtin_amdgcn_sched_barrier(0);
#pragma unroll
        for (int k = 0; k < 10; k++) {
            int i = k * 256 + t;
            if (i < HCHUNK) {
                uint32_t pos = atomicAdd(&hist[dv[k]], 1u);   // LDS-only atomic
                edge_src[pos] = (uint32_t)sv[k];
            }
        }
    }
}

// ---- fallback path (round-5 verified kernels), used only if coop launch fails ----
__global__ __launch_bounds__(256) void count_k(const int* __restrict__ dst,
                                               uint32_t* __restrict__ count2) {
    __shared__ uint32_t hist[N_TYPE];
    int cb = blockIdx.x;
    int t  = threadIdx.x;
#pragma unroll
    for (int i = 0; i < 40; i++) {
        int idx = i * 256 + t;
        if (idx < N_TYPE) hist[idx] = 0u;
    }
    __syncthreads();
    int e0 = cb * HCHUNK;
    int dv[10];
#pragma unroll
    for (int k = 0; k < 10; k++) {
        int i = k * 256 + t;
        dv[k] = dst[e0 + (i < HCHUNK ? i : HCHUNK - 1)];
    }
    __builtin_amdgcn_sched_barrier(0);
#pragma unroll
    for (int k = 0; k < 10; k++) {
        int i = k * 256 + t;
        if (i < HCHUNK) atomicAdd(&hist[dv[k]], 1u);
    }
    __syncthreads();
    uint4* row = (uint4*)(count2 + (size_t)cb * N_TYPE);
#pragma unroll
    for (int i = 0; i < 10; i++) {
        int idx = i * 256 + t;
        if (idx < N_TYPE / 4) row[idx] = ((const uint4*)hist)[idx];
    }
}

__global__ __launch_bounds__(256) void sumscan_k(uint32_t* __restrict__ count2,
                                                 uint32_t* __restrict__ total) {
    int b = blockIdx.x * 256 + (int)threadIdx.x;
    bool ok = b < N_TYPE;
    int bc = ok ? b : N_TYPE - 1;
    uint32_t run = 0;
#pragma unroll
    for (int g = 0; g < HB / 64; g++) {
        uint32_t vals[64];
#pragma unroll
        for (int c = 0; c < 64; c++)
            vals[c] = count2[(size_t)(g * 64 + c) * N_TYPE + bc];
        __builtin_amdgcn_sched_barrier(0);
#pragma unroll
        for (int c = 0; c < 64; c++) { uint32_t v = vals[c]; vals[c] = run; run += v; }
        if (ok) {
#pragma unroll
            for (int c = 0; c < 64; c++)
                count2[(size_t)(g * 64 + c) * N_TYPE + b] = vals[c];
        }
    }
    if (ok) total[b] = run;
}

__global__ __launch_bounds__(1024) void scan_k(const uint32_t* __restrict__ total,
                                               uint32_t* __restrict__ offsets) {
    const int CH = 10;
    int t = threadIdx.x, lane = t & 63, wv = t >> 6;
    int base = t * CH;
    uint32_t local[CH];
    uint32_t tsum = 0;
#pragma unroll
    for (int i = 0; i < CH; i++) {
        int idx = base + i;
        uint32_t c = (idx < N_TYPE) ? total[idx] : 0u;
        local[i] = c;
        tsum += c;
    }
    uint32_t orig = tsum;
#pragma unroll
    for (int off = 1; off < 64; off <<= 1) {
        uint32_t v = __shfl_up(tsum, off, 64);
        if (lane >= off) tsum += v;
    }
    __shared__ uint32_t wsum[16];
    if (lane == 63) wsum[wv] = tsum;
    __syncthreads();
    if (wv == 0 && lane < 16) {
        uint32_t u = wsum[lane], o = u;
#pragma unroll
        for (int off = 1; off < 16; off <<= 1) {
            uint32_t v = __shfl_up(u, off, 64);
            if (lane >= off) u += v;
        }
        wsum[lane] = u - o;
    }
    __syncthreads();
    uint32_t run = wsum[wv] + tsum - orig;
#pragma unroll
    for (int i = 0; i < CH; i++) {
        int idx = base + i;
        if (idx < N_TYPE) {
            offsets[idx] = run;
            run += local[i];
        } else if (idx == N_TYPE) {
            offsets[idx] = run;
        }
    }
}

__global__ __launch_bounds__(256) void fill_k(const int* __restrict__ src,
                                              const int* __restrict__ dst,
                                              const uint32_t* __restrict__ offsets,
                                              const uint32_t* __restrict__ base2,
                                              uint32_t* __restrict__ edge_src) {
    __shared__ uint32_t cur[N_TYPE];
    int cb = blockIdx.x;
    int t  = threadIdx.x;
    const uint32_t* brow = base2 + (size_t)cb * N_TYPE;
#pragma unroll
    for (int i = 0; i < 10; i++) {
        int idx = i * 256 + t;
        if (idx < N_TYPE / 4) {
            uint4 o = ((const uint4*)offsets)[idx];
            uint4 b = ((const uint4*)brow)[idx];
            uint4 c; c.x = o.x + b.x; c.y = o.y + b.y; c.z = o.z + b.z; c.w = o.w + b.w;
            ((uint4*)cur)[idx] = c;
        }
    }
    __syncthreads();
    int e0 = cb * HCHUNK;
    int dv[10], sv[10];
#pragma unroll
    for (int k = 0; k < 10; k++) {
        int i = k * 256 + t;
        int e = e0 + (i < HCHUNK ? i : HCHUNK - 1);
        dv[k] = dst[e];
        sv[k] = src[e];
    }
    __builtin_amdgcn_sched_barrier(0);
#pragma unroll
    for (int k = 0; k < 10; k++) {
        int i = k * 256 + t;
        if (i < HCHUNK) {
            uint32_t pos = atomicAdd(&cur[dv[k]], 1u);
            edge_src[pos] = (uint32_t)sv[k];
        }
    }
}

// ---- one wave per destination: max -> exp-weighted gather-sum (x16/x8) -> normalize
__global__ __launch_bounds__(256) void agg_k(const void* __restrict__ h_sent,
                                             const void* __restrict__ h_type,
                                             const float* __restrict__ s_src,
                                             const float* __restrict__ s_dst,
                                             const uint32_t* __restrict__ offsets,
                                             const uint32_t* __restrict__ edge_src,
                                             void* __restrict__ out) {
    __shared__ float    sc[4][MAXDEG];
    __shared__ uint32_t ss[4][MAXDEG];
    int j     = (blockIdx.x * 256 + threadIdx.x) >> 6;
    int wslot = threadIdx.x >> 6;
    int lane  = threadIdx.x & 63;
    bool valid = j < N_TYPE;
    bool isbf  = detect_bf16((const uint32_t*)h_sent);
    uint32_t beg = 0, deg = 0;
    float sdj = 0.0f;
    if (valid) {
        beg = offsets[j];
        deg = offsets[j + 1] - beg;
        sdj = s_dst[j];
    }
    float*    mysc = sc[wslot];
    uint32_t* myss = ss[wslot];
    bool fits = (deg <= MAXDEG);
    float m = -INFINITY;
    for (uint32_t k = lane; k < deg; k += 64) {
        uint32_t s = edge_src[beg + k];
        float v = s_src[s] + sdj;
        v = v > 0.0f ? v : 0.01f * v;
        if (fits) { mysc[k] = v; myss[k] = s; }
        m = fmaxf(m, v);
    }
#pragma unroll
    for (int off = 32; off; off >>= 1) m = fmaxf(m, __shfl_xor(m, off, 64));
    __syncthreads();   // LDS visibility (uniform: every thread reaches this)
    if (!valid) return;
    if (deg == 0) {    // isolated node keeps its input feature
        if (isbf) ((uint32_t*)out)[(size_t)j * 64 + lane] =
                      ((const uint32_t*)h_type)[(size_t)j * 64 + lane];
        else      ((float2*)out)[(size_t)j * 64 + lane] =
                      ((const float2*)h_type)[(size_t)j * 64 + lane];
        return;
    }
    float denom = 0.0f, a0 = 0.0f, a1 = 0.0f;
    if (isbf) {
        const uint32_t* hp = (const uint32_t*)h_sent;
        uint32_t k = 0;
        if (fits) {
            for (; k + 16 <= deg; k += 16) {
                uint32_t sv[16]; float vv[16]; uint32_t gv[16];
#pragma unroll
                for (int i = 0; i < 16; i++) { sv[i] = myss[k + i]; vv[i] = mysc[k + i]; }
#pragma unroll
                for (int i = 0; i < 16; i++) gv[i] = hp[(size_t)sv[i] * 64 + lane];
#pragma unroll
                for (int i = 0; i < 16; i++) {
                    float w = __expf(vv[i] - m);
                    denom += w;
                    a0 += w * bf2f(gv[i] & 0xffffu);
                    a1 += w * bf2f(gv[i] >> 16);
                }
            }
            for (; k + 8 <= deg; k += 8) {
                uint32_t sv[8]; float vv[8]; uint32_t gv[8];
#pragma unroll
                for (int i = 0; i < 8; i++) { sv[i] = myss[k + i]; vv[i] = mysc[k + i]; }
#pragma unroll
                for (int i = 0; i < 8; i++) gv[i] = hp[(size_t)sv[i] * 64 + lane];
#pragma unroll
                for (int i = 0; i < 8; i++) {
                    float w = __expf(vv[i] - m);
                    denom += w;
                    a0 += w * bf2f(gv[i] & 0xffffu);
                    a1 += w * bf2f(gv[i] >> 16);
                }
            }
            for (; k < deg; ++k) {
                float w = __expf(mysc[k] - m);
                uint32_t g = hp[(size_t)myss[k] * 64 + lane];
                denom += w;
                a0 += w * bf2f(g & 0xffffu);
                a1 += w * bf2f(g >> 16);
            }
        } else {
            for (k = 0; k < deg; ++k) {
                uint32_t s = edge_src[beg + k];
                float v = s_src[s] + sdj; v = v > 0.0f ? v : 0.01f * v;
                float w = __expf(v - m);
                uint32_t g = hp[(size_t)s * 64 + lane];
                denom += w;
                a0 += w * bf2f(g & 0xffffu);
                a1 += w * bf2f(g >> 16);
            }
        }
        float inv = 1.0f / denom;
        ((uint32_t*)out)[(size_t)j * 64 + lane] = f2bf(a0 * inv) | (f2bf(a1 * inv) << 16);
    } else {
        const float2* hp = (const float2*)h_sent;
        uint32_t k = 0;
        if (fits) {
            for (; k + 16 <= deg; k += 16) {
                uint32_t sv[16]; float vv[16]; float2 gv[16];
#pragma unroll
                for (int i = 0; i < 16; i++) { sv[i] = myss[k + i]; vv[i] = mysc[k + i]; }
#pragma unroll
                for (int i = 0; i < 16; i++) gv[i] = hp[(size_t)sv[i] * 64 + lane];
#pragma unroll
                for (int i = 0; i < 16; i++) {
                    float w = __expf(vv[i] - m);
                    denom += w;
                    a0 += w * gv[i].x;
                    a1 += w * gv[i].y;
                }
            }
            for (; k + 8 <= deg; k += 8) {
                uint32_t sv[8]; float vv[8]; float2 gv[8];
#pragma unroll
                for (int i = 0; i < 8; i++) { sv[i] = myss[k + i]; vv[i] = mysc[k + i]; }
#pragma unroll
                for (int i = 0; i < 8; i++) gv[i] = hp[(size_t)sv[i] * 64 + lane];
#pragma unroll
                for (int i = 0; i < 8; i++) {
                    float w = __expf(vv[i] - m);
                    denom += w;
                    a0 += w * gv[i].x;
                    a1 += w * gv[i].y;
                }
            }
            for (; k < deg; ++k) {
                float w = __expf(mysc[k] - m);
                float2 g = hp[(size_t)myss[k] * 64 + lane];
                denom += w;
                a0 += w * g.x;
                a1 += w * g.y;
            }
        } else {
            for (k = 0; k < deg; ++k) {
                uint32_t s = edge_src[beg + k];
                float v = s_src[s] + sdj; v = v > 0.0f ? v : 0.01f * v;
                float w = __expf(v - m);
                float2 g = hp[(size_t)s * 64 + lane];
                denom += w;
                a0 += w * g.x;
                a1 += w * g.y;
            }
        }
        float inv = 1.0f / denom;
        ((float2*)out)[(size_t)j * 64 + lane] = make_float2(a0 * inv, a1 * inv);
    }
}

static inline size_t align_up(size_t x) { return (x + 255) & ~(size_t)255; }

extern "C" void kernel_launch(void* const* d_in, const int* in_sizes, int n_in,
                              void* d_out, int out_size, void* d_ws, size_t ws_size,
                              hipStream_t stream) {
    const void* h_sent = d_in[0];
    const void* h_type = d_in[1];
    const void* attn_w = d_in[2];
    const int* src_idx = (const int*)d_in[3];
    const int* dst_idx = (const int*)d_in[4];

    char* w = (char*)d_ws;
    float*    s_src     = (float*)w;    w += align_up((size_t)N_SENT * 4);
    float*    s_dst     = (float*)w;    w += align_up((size_t)N_TYPE * 4);
    uint32_t* count2    = (uint32_t*)w; w += align_up((size_t)HB * N_TYPE * 4);  // 10.24 MB
    uint32_t* total     = (uint32_t*)w; w += align_up((size_t)N_TYPE * 4);
    uint32_t* offsets   = (uint32_t*)w; w += align_up((size_t)(N_TYPE + 1) * 4);
    uint32_t* edge_src  = (uint32_t*)w; w += align_up((size_t)NEDGE * 4);
    // total ~13.4 MB

    scores_k<<<SC_BLOCKS, 256, 0, stream>>>(h_sent, h_type, attn_w, s_src, s_dst);

    void* args[] = { (void*)&src_idx, (void*)&dst_idx, (void*)&count2,
                     (void*)&total, (void*)&offsets, (void*)&edge_src };
    hipError_t cerr = hipLaunchCooperativeKernel((void*)build2_k, dim3(256), dim3(256),
                                                 args, 0, stream);
    if (cerr != hipSuccess) {
        // fallback: round-5 verified 4-kernel CSR build
        count_k<<<HB, 256, 0, stream>>>(dst_idx, count2);
        sumscan_k<<<(N_TYPE + 255) / 256, 256, 0, stream>>>(count2, total);
        scan_k<<<1, 1024, 0, stream>>>(total, offsets);
        fill_k<<<HB, 256, 0, stream>>>(src_idx, dst_idx, offsets, count2, edge_src);
    }

    agg_k<<<(N_TYPE + 3) / 4, 256, 0, stream>>>(h_sent, h_type, s_src, s_dst,
                                                offsets, edge_src, d_out);
}

// Round 8
// 175.904 us; speedup vs baseline: 1.6152x; 1.6152x over previous
//
#include <hip/hip_runtime.h>
#include <stdint.h>
#include <stddef.h>

#define N_SENT 100000
#define N_TYPE 10000
#define NEDGE  640000
#define NROWS  (N_SENT + N_TYPE)
#define MAXDEG 256    // LDS cache per wave in agg_k; Poisson(64): P(deg>256) ~ 0. Fallback exists.
#define HB     256    // histogram chunks; 256 * 2500 == NEDGE exactly
#define HCHUNK (NEDGE / HB)   // 2500

__device__ __forceinline__ float bf2f(uint32_t lo16) {
    return __builtin_bit_cast(float, lo16 << 16);
}
__device__ __forceinline__ uint32_t f2bf(float f) {
    uint32_t u = __builtin_bit_cast(uint32_t, f);
    return (u + 0x7fffu + ((u >> 16) & 1u)) >> 16;
}

// Inline per-wave dtype probe: bf16 pairs have bf16-sane exponents in the low halfword;
// f32 low halfwords are mantissa bits (uniform). One broadcast load + ballot, wave-uniform.
__device__ __forceinline__ bool detect_bf16(const uint32_t* __restrict__ h) {
    uint32_t u = h[threadIdx.x & 63];
    uint32_t e_lo = (u >> 7) & 0xffu;
    int ok = (e_lo >= 100u && e_lo <= 140u) ? 1 : 0;
    unsigned long long m = __ballot(ok);
    return __popcll(m) >= 48;
}

// ---- scores: streaming matvec (round-5 version, verified) ----
#define SC_BLOCKS 6875   // 6875*256 = 1,760,000 = NROWS*16 (bf16 chunks) = (NROWS*32)/2 (f32)

__global__ __launch_bounds__(256) void scores_k(const void* __restrict__ h_sent,
                                                const void* __restrict__ h_type,
                                                const void* __restrict__ attn_w,
                                                float* __restrict__ s_src,
                                                float* __restrict__ s_dst) {
    int t    = blockIdx.x * 256 + (int)threadIdx.x;
    int lane = threadIdx.x & 63;
    bool isbf = detect_bf16((const uint32_t*)h_sent);
    if (isbf) {
        uint4 wsv = ((const uint4*)attn_w)[lane & 15];        // 8 bf16 dims of w[:D]
        uint4 wtv = ((const uint4*)attn_w)[16 + (lane & 15)]; // 8 bf16 dims of w[D:]
        bool isSrc = t < N_SENT * 16;
        const uint4* p = isSrc ? (const uint4*)h_sent + t
                               : (const uint4*)h_type + (t - N_SENT * 16);
        uint4 h = *p;
        uint4 wv = isSrc ? wsv : wtv;
        float s = bf2f(h.x & 0xffffu) * bf2f(wv.x & 0xffffu)
                + bf2f(h.x >> 16)     * bf2f(wv.x >> 16)
                + bf2f(h.y & 0xffffu) * bf2f(wv.y & 0xffffu)
                + bf2f(h.y >> 16)     * bf2f(wv.y >> 16)
                + bf2f(h.z & 0xffffu) * bf2f(wv.z & 0xffffu)
                + bf2f(h.z >> 16)     * bf2f(wv.z >> 16)
                + bf2f(h.w & 0xffffu) * bf2f(wv.w & 0xffffu)
                + bf2f(h.w >> 16)     * bf2f(wv.w >> 16);
        s += __shfl_xor(s, 1, 64);
        s += __shfl_xor(s, 2, 64);
        s += __shfl_xor(s, 4, 64);
        s += __shfl_xor(s, 8, 64);
        if ((lane & 15) == 0) {
            int row = t >> 4;
            if (row < N_SENT) s_src[row] = s;
            else              s_dst[row - N_SENT] = s;
        }
    } else {
        float4 wsv = ((const float4*)attn_w)[lane & 31];        // 4 f32 dims of w[:D]
        float4 wtv = ((const float4*)attn_w)[32 + (lane & 31)]; // 4 f32 dims of w[D:]
        const int HALF = NROWS * 16;   // items total = NROWS*32
        int it0 = t, it1 = t + HALF;   // both ≡ lane (mod 32)
        bool s0 = it0 < N_SENT * 32, s1 = it1 < N_SENT * 32;
        const float4* p0 = s0 ? (const float4*)h_sent + it0
                              : (const float4*)h_type + (it0 - N_SENT * 32);
        const float4* p1 = s1 ? (const float4*)h_sent + it1
                              : (const float4*)h_type + (it1 - N_SENT * 32);
        float4 h0 = *p0;
        float4 h1 = *p1;
        __builtin_amdgcn_sched_barrier(0);   // both loads in flight
        float4 w0 = s0 ? wsv : wtv, w1 = s1 ? wsv : wtv;
        float a = h0.x * w0.x + h0.y * w0.y + h0.z * w0.z + h0.w * w0.w;
        float b = h1.x * w1.x + h1.y * w1.y + h1.z * w1.z + h1.w * w1.w;
        a += __shfl_xor(a, 1, 64);  b += __shfl_xor(b, 1, 64);
        a += __shfl_xor(a, 2, 64);  b += __shfl_xor(b, 2, 64);
        a += __shfl_xor(a, 4, 64);  b += __shfl_xor(b, 4, 64);
        a += __shfl_xor(a, 8, 64);  b += __shfl_xor(b, 8, 64);
        a += __shfl_xor(a, 16, 64); b += __shfl_xor(b, 16, 64);
        if ((lane & 31) == 0) {
            int r0 = it0 >> 5, r1 = it1 >> 5;
            if (r0 < N_SENT) s_src[r0] = a; else s_dst[r0 - N_SENT] = a;
            if (r1 < N_SENT) s_src[r1] = b; else s_dst[r1 - N_SENT] = b;
        }
    }
}

// ---- count: 256 blocks x 2500-edge chunk; upfront dst loads (MLP), uint4 writeback ----
__global__ __launch_bounds__(256) void count_k(const int* __restrict__ dst,
                                               uint32_t* __restrict__ count2) {
    __shared__ uint32_t hist[N_TYPE];   // 40 KB
    int cb = blockIdx.x;                // [0, HB)
    int t  = threadIdx.x;
#pragma unroll
    for (int i = 0; i < 40; i++) {      // 40*256 >= N_TYPE
        int idx = i * 256 + t;
        if (idx < N_TYPE) hist[idx] = 0u;
    }
    __syncthreads();
    int e0 = cb * HCHUNK;
    int dv[10];                          // HCHUNK = 2500 <= 10*256
#pragma unroll
    for (int k = 0; k < 10; k++) {
        int i = k * 256 + t;
        dv[k] = dst[e0 + (i < HCHUNK ? i : HCHUNK - 1)];
    }
    __builtin_amdgcn_sched_barrier(0);   // all 10 loads in flight
#pragma unroll
    for (int k = 0; k < 10; k++) {
        int i = k * 256 + t;
        if (i < HCHUNK) atomicAdd(&hist[dv[k]], 1u);
    }
    __syncthreads();
    uint4* row = (uint4*)(count2 + (size_t)cb * N_TYPE);
#pragma unroll
    for (int i = 0; i < 10; i++) {       // 2500 uint4 = 10000 words
        int idx = i * 256 + t;
        if (idx < N_TYPE / 4) row[idx] = ((const uint4*)hist)[idx];
    }
}

// ---- column exclusive-scan, 8-way parallel: 8 lanes per bin, 32 chunks per lane ----
// Round-5 version used 40 blocks (15% of CUs) -> latency-bound ~30-40us (inferred).
// This spreads each column over 8 lanes with an in-wave segmented shfl scan: 313 blocks.
__global__ __launch_bounds__(256) void sumscan_k(uint32_t* __restrict__ count2,
                                                 uint32_t* __restrict__ total) {
    int tid  = blockIdx.x * 256 + (int)threadIdx.x;
    int lane = threadIdx.x & 63;
    int bin  = tid >> 3;                 // 8 lanes per bin (wave covers 8 bins)
    int sub  = tid & 7;                  // chunk sub-range [sub*32, sub*32+32)
    if (bin >= N_TYPE) return;
    uint32_t vals[32];
#pragma unroll
    for (int c = 0; c < 32; c++)         // 32 independent loads
        vals[c] = count2[(size_t)(sub * 32 + c) * N_TYPE + bin];
    __builtin_amdgcn_sched_barrier(0);
    uint32_t lsum = 0;
#pragma unroll
    for (int c = 0; c < 32; c++) lsum += vals[c];
    // segmented inclusive scan across the 8 subs (lane&7 groups)
    uint32_t incl = lsum;
#pragma unroll
    for (int off = 1; off < 8; off <<= 1) {
        uint32_t v = __shfl_up(incl, off, 64);
        if ((lane & 7) >= off) incl += v;
    }
    uint32_t run = incl - lsum;          // exclusive base of this sub within the column
#pragma unroll
    for (int c = 0; c < 32; c++) {
        uint32_t v = vals[c];
        count2[(size_t)(sub * 32 + c) * N_TYPE + bin] = run;
        run += v;
    }
    if (sub == 7) total[bin] = incl;     // full column sum
}

// ---- single-block exclusive scan of totals -> offsets[N_TYPE+1] ----
__global__ __launch_bounds__(1024) void scan_k(const uint32_t* __restrict__ total,
                                               uint32_t* __restrict__ offsets) {
    const int CH = 10;   // 1024*10 >= N_TYPE
    int t = threadIdx.x, lane = t & 63, wv = t >> 6;   // 16 waves
    int base = t * CH;
    uint32_t local[CH];
    uint32_t tsum = 0;
#pragma unroll
    for (int i = 0; i < CH; i++) {
        int idx = base + i;
        uint32_t c = (idx < N_TYPE) ? total[idx] : 0u;
        local[i] = c;
        tsum += c;
    }
    uint32_t orig = tsum;
#pragma unroll
    for (int off = 1; off < 64; off <<= 1) {
        uint32_t v = __shfl_up(tsum, off, 64);
        if (lane >= off) tsum += v;
    }
    __shared__ uint32_t wsum[16];
    if (lane == 63) wsum[wv] = tsum;
    __syncthreads();
    if (wv == 0 && lane < 16) {
        uint32_t u = wsum[lane], o = u;
#pragma unroll
        for (int off = 1; off < 16; off <<= 1) {
            uint32_t v = __shfl_up(u, off, 64);
            if (lane >= off) u += v;
        }
        wsum[lane] = u - o;   // exclusive wave prefix
    }
    __syncthreads();
    uint32_t run = wsum[wv] + tsum - orig;   // exclusive thread prefix
#pragma unroll
    for (int i = 0; i < CH; i++) {
        int idx = base + i;
        if (idx < N_TYPE) {
            offsets[idx] = run;
            run += local[i];
        } else if (idx == N_TYPE) {
            offsets[idx] = run;   // == NEDGE
        }
    }
}

// ---- fill: 256 blocks; uint4 cursor init; upfront edge loads; LDS-atomic scatter ----
__global__ __launch_bounds__(256) void fill_k(const int* __restrict__ src,
                                              const int* __restrict__ dst,
                                              const uint32_t* __restrict__ offsets,
                                              const uint32_t* __restrict__ base2,
                                              uint32_t* __restrict__ edge_src) {
    __shared__ uint32_t cur[N_TYPE];   // 40 KB
    int cb = blockIdx.x;               // [0, HB)
    int t  = threadIdx.x;
    const uint32_t* brow = base2 + (size_t)cb * N_TYPE;
#pragma unroll
    for (int i = 0; i < 10; i++) {     // 2500 uint4 covers 10000 bins
        int idx = i * 256 + t;
        if (idx < N_TYPE / 4) {
            uint4 o = ((const uint4*)offsets)[idx];
            uint4 b = ((const uint4*)brow)[idx];
            uint4 c; c.x = o.x + b.x; c.y = o.y + b.y; c.z = o.z + b.z; c.w = o.w + b.w;
            ((uint4*)cur)[idx] = c;
        }
    }
    __syncthreads();
    int e0 = cb * HCHUNK;
    int dv[10], sv[10];
#pragma unroll
    for (int k = 0; k < 10; k++) {      // all 20 loads upfront
        int i = k * 256 + t;
        int e = e0 + (i < HCHUNK ? i : HCHUNK - 1);
        dv[k] = dst[e];
        sv[k] = src[e];
    }
    __builtin_amdgcn_sched_barrier(0);
#pragma unroll
    for (int k = 0; k < 10; k++) {
        int i = k * 256 + t;
        if (i < HCHUNK) {
            uint32_t pos = atomicAdd(&cur[dv[k]], 1u);   // LDS-only atomic
            edge_src[pos] = (uint32_t)sv[k];
        }
    }
}

// ---- one wave per destination: max -> exp-weighted gather-sum (x16/x8) -> normalize
__global__ __launch_bounds__(256) void agg_k(const void* __restrict__ h_sent,
                                             const void* __restrict__ h_type,
                                             const float* __restrict__ s_src,
                                             const float* __restrict__ s_dst,
                                             const uint32_t* __restrict__ offsets,
                                             const uint32_t* __restrict__ edge_src,
                                             void* __restrict__ out) {
    __shared__ float    sc[4][MAXDEG];
    __shared__ uint32_t ss[4][MAXDEG];
    int j     = (blockIdx.x * 256 + threadIdx.x) >> 6;
    int wslot = threadIdx.x >> 6;
    int lane  = threadIdx.x & 63;
    bool valid = j < N_TYPE;
    bool isbf  = detect_bf16((const uint32_t*)h_sent);
    uint32_t beg = 0, deg = 0;
    float sdj = 0.0f;
    if (valid) {
        beg = offsets[j];
        deg = offsets[j + 1] - beg;
        sdj = s_dst[j];
    }
    float*    mysc = sc[wslot];
    uint32_t* myss = ss[wslot];
    bool fits = (deg <= MAXDEG);
    float m = -INFINITY;
    for (uint32_t k = lane; k < deg; k += 64) {
        uint32_t s = edge_src[beg + k];
        float v = s_src[s] + sdj;
        v = v > 0.0f ? v : 0.01f * v;
        if (fits) { mysc[k] = v; myss[k] = s; }
        m = fmaxf(m, v);
    }
#pragma unroll
    for (int off = 32; off; off >>= 1) m = fmaxf(m, __shfl_xor(m, off, 64));
    __syncthreads();   // LDS visibility (uniform: every thread reaches this)
    if (!valid) return;
    if (deg == 0) {    // isolated node keeps its input feature
        if (isbf) ((uint32_t*)out)[(size_t)j * 64 + lane] =
                      ((const uint32_t*)h_type)[(size_t)j * 64 + lane];
        else      ((float2*)out)[(size_t)j * 64 + lane] =
                      ((const float2*)h_type)[(size_t)j * 64 + lane];
        return;
    }
    float denom = 0.0f, a0 = 0.0f, a1 = 0.0f;
    if (isbf) {
        const uint32_t* hp = (const uint32_t*)h_sent;
        uint32_t k = 0;
        if (fits) {
            for (; k + 16 <= deg; k += 16) {               // 16 row-loads in flight
                uint32_t sv[16]; float vv[16]; uint32_t gv[16];
#pragma unroll
                for (int i = 0; i < 16; i++) { sv[i] = myss[k + i]; vv[i] = mysc[k + i]; }
#pragma unroll
                for (int i = 0; i < 16; i++) gv[i] = hp[(size_t)sv[i] * 64 + lane];
#pragma unroll
                for (int i = 0; i < 16; i++) {
                    float w = __expf(vv[i] - m);
                    denom += w;
                    a0 += w * bf2f(gv[i] & 0xffffu);
                    a1 += w * bf2f(gv[i] >> 16);
                }
            }
            for (; k + 8 <= deg; k += 8) {                 // 8-wide cleanup
                uint32_t sv[8]; float vv[8]; uint32_t gv[8];
#pragma unroll
                for (int i = 0; i < 8; i++) { sv[i] = myss[k + i]; vv[i] = mysc[k + i]; }
#pragma unroll
                for (int i = 0; i < 8; i++) gv[i] = hp[(size_t)sv[i] * 64 + lane];
#pragma unroll
                for (int i = 0; i < 8; i++) {
                    float w = __expf(vv[i] - m);
                    denom += w;
                    a0 += w * bf2f(gv[i] & 0xffffu);
                    a1 += w * bf2f(gv[i] >> 16);
                }
            }
            for (; k < deg; ++k) {
                float w = __expf(mysc[k] - m);
                uint32_t g = hp[(size_t)myss[k] * 64 + lane];
                denom += w;
                a0 += w * bf2f(g & 0xffffu);
                a1 += w * bf2f(g >> 16);
            }
        } else {
            for (k = 0; k < deg; ++k) {
                uint32_t s = edge_src[beg + k];
                float v = s_src[s] + sdj; v = v > 0.0f ? v : 0.01f * v;
                float w = __expf(v - m);
                uint32_t g = hp[(size_t)s * 64 + lane];
                denom += w;
                a0 += w * bf2f(g & 0xffffu);
                a1 += w * bf2f(g >> 16);
            }
        }
        float inv = 1.0f / denom;
        ((uint32_t*)out)[(size_t)j * 64 + lane] = f2bf(a0 * inv) | (f2bf(a1 * inv) << 16);
    } else {
        const float2* hp = (const float2*)h_sent;
        uint32_t k = 0;
        if (fits) {
            for (; k + 16 <= deg; k += 16) {               // 16 row-loads in flight
                uint32_t sv[16]; float vv[16]; float2 gv[16];
#pragma unroll
                for (int i = 0; i < 16; i++) { sv[i] = myss[k + i]; vv[i] = mysc[k + i]; }
#pragma unroll
                for (int i = 0; i < 16; i++) gv[i] = hp[(size_t)sv[i] * 64 + lane];
#pragma unroll
                for (int i = 0; i < 16; i++) {
                    float w = __expf(vv[i] - m);
                    denom += w;
                    a0 += w * gv[i].x;
                    a1 += w * gv[i].y;
                }
            }
            for (; k + 8 <= deg; k += 8) {                 // 8-wide cleanup
                uint32_t sv[8]; float vv[8]; float2 gv[8];
#pragma unroll
                for (int i = 0; i < 8; i++) { sv[i] = myss[k + i]; vv[i] = mysc[k + i]; }
#pragma unroll
                for (int i = 0; i < 8; i++) gv[i] = hp[(size_t)sv[i] * 64 + lane];
#pragma unroll
                for (int i = 0; i < 8; i++) {
                    float w = __expf(vv[i] - m);
                    denom += w;
                    a0 += w * gv[i].x;
                    a1 += w * gv[i].y;
                }
            }
            for (; k < deg; ++k) {
                float w = __expf(mysc[k] - m);
                float2 g = hp[(size_t)myss[k] * 64 + lane];
                denom += w;
                a0 += w * g.x;
                a1 += w * g.y;
            }
        } else {
            for (k = 0; k < deg; ++k) {
                uint32_t s = edge_src[beg + k];
                float v = s_src[s] + sdj; v = v > 0.0f ? v : 0.01f * v;
                float w = __expf(v - m);
                float2 g = hp[(size_t)s * 64 + lane];
                denom += w;
                a0 += w * g.x;
                a1 += w * g.y;
            }
        }
        float inv = 1.0f / denom;
        ((float2*)out)[(size_t)j * 64 + lane] = make_float2(a0 * inv, a1 * inv);
    }
}

static inline size_t align_up(size_t x) { return (x + 255) & ~(size_t)255; }

extern "C" void kernel_launch(void* const* d_in, const int* in_sizes, int n_in,
                              void* d_out, int out_size, void* d_ws, size_t ws_size,
                              hipStream_t stream) {
    const void* h_sent = d_in[0];
    const void* h_type = d_in[1];
    const void* attn_w = d_in[2];
    const int* src_idx = (const int*)d_in[3];
    const int* dst_idx = (const int*)d_in[4];

    char* w = (char*)d_ws;
    float*    s_src     = (float*)w;    w += align_up((size_t)N_SENT * 4);
    float*    s_dst     = (float*)w;    w += align_up((size_t)N_TYPE * 4);
    uint32_t* count2    = (uint32_t*)w; w += align_up((size_t)HB * N_TYPE * 4);  // 10.24 MB
    uint32_t* total     = (uint32_t*)w; w += align_up((size_t)N_TYPE * 4);
    uint32_t* offsets   = (uint32_t*)w; w += align_up((size_t)(N_TYPE + 1) * 4);
    uint32_t* edge_src  = (uint32_t*)w; w += align_up((size_t)NEDGE * 4);
    // total ~13.4 MB

    scores_k<<<SC_BLOCKS, 256, 0, stream>>>(h_sent, h_type, attn_w, s_src, s_dst);
    count_k<<<HB, 256, 0, stream>>>(dst_idx, count2);
    sumscan_k<<<(N_TYPE * 8 + 255) / 256, 256, 0, stream>>>(count2, total);
    scan_k<<<1, 1024, 0, stream>>>(total, offsets);
    fill_k<<<HB, 256, 0, stream>>>(src_idx, dst_idx, offsets, count2, edge_src);
    agg_k<<<(N_TYPE + 3) / 4, 256, 0, stream>>>(h_sent, h_type, s_src, s_dst,
                                                offsets, edge_src, d_out);
}

// Round 9
// 174.589 us; speedup vs baseline: 1.6274x; 1.0075x over previous
//
#include <hip/hip_runtime.h>
#include <stdint.h>
#include <stddef.h>

#define N_SENT 100000
#define N_TYPE 10000
#define NEDGE  640000
#define NROWS  (N_SENT + N_TYPE)
#define MAXDEG 256    // LDS cache per wave in agg_k; Poisson(64): P(deg>256) ~ 0. Fallback exists.
#define HB     256    // histogram chunks; 256 * 2500 == NEDGE exactly
#define HCHUNK (NEDGE / HB)   // 2500

__device__ __forceinline__ float bf2f(uint32_t lo16) {
    return __builtin_bit_cast(float, lo16 << 16);
}
__device__ __forceinline__ uint32_t f2bf(float f) {
    uint32_t u = __builtin_bit_cast(uint32_t, f);
    return (u + 0x7fffu + ((u >> 16) & 1u)) >> 16;
}

// Inline per-wave dtype probe: bf16 pairs have bf16-sane exponents in the low halfword;
// f32 low halfwords are mantissa bits (uniform). One broadcast load + ballot, wave-uniform.
__device__ __forceinline__ bool detect_bf16(const uint32_t* __restrict__ h) {
    uint32_t u = h[threadIdx.x & 63];
    uint32_t e_lo = (u >> 7) & 0xffu;
    int ok = (e_lo >= 100u && e_lo <= 140u) ? 1 : 0;
    unsigned long long m = __ballot(ok);
    return __popcll(m) >= 48;
}

// ---- scores: streaming matvec (round-5 version, verified) ----
#define SC_BLOCKS 6875   // 6875*256 = 1,760,000 = NROWS*16 (bf16 chunks) = (NROWS*32)/2 (f32)

__global__ __launch_bounds__(256) void scores_k(const void* __restrict__ h_sent,
                                                const void* __restrict__ h_type,
                                                const void* __restrict__ attn_w,
                                                float* __restrict__ s_src,
                                                float* __restrict__ s_dst) {
    int t    = blockIdx.x * 256 + (int)threadIdx.x;
    int lane = threadIdx.x & 63;
    bool isbf = detect_bf16((const uint32_t*)h_sent);
    if (isbf) {
        uint4 wsv = ((const uint4*)attn_w)[lane & 15];        // 8 bf16 dims of w[:D]
        uint4 wtv = ((const uint4*)attn_w)[16 + (lane & 15)]; // 8 bf16 dims of w[D:]
        bool isSrc = t < N_SENT * 16;
        const uint4* p = isSrc ? (const uint4*)h_sent + t
                               : (const uint4*)h_type + (t - N_SENT * 16);
        uint4 h = *p;
        uint4 wv = isSrc ? wsv : wtv;
        float s = bf2f(h.x & 0xffffu) * bf2f(wv.x & 0xffffu)
                + bf2f(h.x >> 16)     * bf2f(wv.x >> 16)
                + bf2f(h.y & 0xffffu) * bf2f(wv.y & 0xffffu)
                + bf2f(h.y >> 16)     * bf2f(wv.y >> 16)
                + bf2f(h.z & 0xffffu) * bf2f(wv.z & 0xffffu)
                + bf2f(h.z >> 16)     * bf2f(wv.z >> 16)
                + bf2f(h.w & 0xffffu) * bf2f(wv.w & 0xffffu)
                + bf2f(h.w >> 16)     * bf2f(wv.w >> 16);
        s += __shfl_xor(s, 1, 64);
        s += __shfl_xor(s, 2, 64);
        s += __shfl_xor(s, 4, 64);
        s += __shfl_xor(s, 8, 64);
        if ((lane & 15) == 0) {
            int row = t >> 4;
            if (row < N_SENT) s_src[row] = s;
            else              s_dst[row - N_SENT] = s;
        }
    } else {
        float4 wsv = ((const float4*)attn_w)[lane & 31];        // 4 f32 dims of w[:D]
        float4 wtv = ((const float4*)attn_w)[32 + (lane & 31)]; // 4 f32 dims of w[D:]
        const int HALF = NROWS * 16;   // items total = NROWS*32
        int it0 = t, it1 = t + HALF;   // both ≡ lane (mod 32)
        bool s0 = it0 < N_SENT * 32, s1 = it1 < N_SENT * 32;
        const float4* p0 = s0 ? (const float4*)h_sent + it0
                              : (const float4*)h_type + (it0 - N_SENT * 32);
        const float4* p1 = s1 ? (const float4*)h_sent + it1
                              : (const float4*)h_type + (it1 - N_SENT * 32);
        float4 h0 = *p0;
        float4 h1 = *p1;
        __builtin_amdgcn_sched_barrier(0);   // both loads in flight
        float4 w0 = s0 ? wsv : wtv, w1 = s1 ? wsv : wtv;
        float a = h0.x * w0.x + h0.y * w0.y + h0.z * w0.z + h0.w * w0.w;
        float b = h1.x * w1.x + h1.y * w1.y + h1.z * w1.z + h1.w * w1.w;
        a += __shfl_xor(a, 1, 64);  b += __shfl_xor(b, 1, 64);
        a += __shfl_xor(a, 2, 64);  b += __shfl_xor(b, 2, 64);
        a += __shfl_xor(a, 4, 64);  b += __shfl_xor(b, 4, 64);
        a += __shfl_xor(a, 8, 64);  b += __shfl_xor(b, 8, 64);
        a += __shfl_xor(a, 16, 64); b += __shfl_xor(b, 16, 64);
        if ((lane & 31) == 0) {
            int r0 = it0 >> 5, r1 = it1 >> 5;
            if (r0 < N_SENT) s_src[r0] = a; else s_dst[r0 - N_SENT] = a;
            if (r1 < N_SENT) s_src[r1] = b; else s_dst[r1 - N_SENT] = b;
        }
    }
}

// ---- count: 256 blocks x 2500-edge chunk; upfront dst loads (MLP), uint4 writeback ----
__global__ __launch_bounds__(256) void count_k(const int* __restrict__ dst,
                                               uint32_t* __restrict__ count2) {
    __shared__ uint32_t hist[N_TYPE];   // 40 KB
    int cb = blockIdx.x;                // [0, HB)
    int t  = threadIdx.x;
#pragma unroll
    for (int i = 0; i < 40; i++) {      // 40*256 >= N_TYPE
        int idx = i * 256 + t;
        if (idx < N_TYPE) hist[idx] = 0u;
    }
    __syncthreads();
    int e0 = cb * HCHUNK;
    int dv[10];                          // HCHUNK = 2500 <= 10*256
#pragma unroll
    for (int k = 0; k < 10; k++) {
        int i = k * 256 + t;
        dv[k] = dst[e0 + (i < HCHUNK ? i : HCHUNK - 1)];
    }
    __builtin_amdgcn_sched_barrier(0);   // all 10 loads in flight
#pragma unroll
    for (int k = 0; k < 10; k++) {
        int i = k * 256 + t;
        if (i < HCHUNK) atomicAdd(&hist[dv[k]], 1u);
    }
    __syncthreads();
    uint4* row = (uint4*)(count2 + (size_t)cb * N_TYPE);
#pragma unroll
    for (int i = 0; i < 10; i++) {       // 2500 uint4 = 10000 words
        int idx = i * 256 + t;
        if (idx < N_TYPE / 4) row[idx] = ((const uint4*)hist)[idx];
    }
}

// ---- column exclusive-scan, 8-way parallel: 8 lanes per bin, 32 chunks per lane ----
__global__ __launch_bounds__(256) void sumscan_k(uint32_t* __restrict__ count2,
                                                 uint32_t* __restrict__ total) {
    int tid  = blockIdx.x * 256 + (int)threadIdx.x;
    int lane = threadIdx.x & 63;
    int bin  = tid >> 3;                 // 8 lanes per bin (wave covers 8 bins)
    int sub  = tid & 7;                  // chunk sub-range [sub*32, sub*32+32)
    if (bin >= N_TYPE) return;
    uint32_t vals[32];
#pragma unroll
    for (int c = 0; c < 32; c++)         // 32 independent loads
        vals[c] = count2[(size_t)(sub * 32 + c) * N_TYPE + bin];
    __builtin_amdgcn_sched_barrier(0);
    uint32_t lsum = 0;
#pragma unroll
    for (int c = 0; c < 32; c++) lsum += vals[c];
    // segmented inclusive scan across the 8 subs (lane&7 groups)
    uint32_t incl = lsum;
#pragma unroll
    for (int off = 1; off < 8; off <<= 1) {
        uint32_t v = __shfl_up(incl, off, 64);
        if ((lane & 7) >= off) incl += v;
    }
    uint32_t run = incl - lsum;          // exclusive base of this sub within the column
#pragma unroll
    for (int c = 0; c < 32; c++) {
        uint32_t v = vals[c];
        count2[(size_t)(sub * 32 + c) * N_TYPE + bin] = run;
        run += v;
    }
    if (sub == 7) total[bin] = incl;     // full column sum
}

// ---- single-block exclusive scan of totals -> offsets[N_TYPE+1] ----
__global__ __launch_bounds__(1024) void scan_k(const uint32_t* __restrict__ total,
                                               uint32_t* __restrict__ offsets) {
    const int CH = 10;   // 1024*10 >= N_TYPE
    int t = threadIdx.x, lane = t & 63, wv = t >> 6;   // 16 waves
    int base = t * CH;
    uint32_t local[CH];
    uint32_t tsum = 0;
#pragma unroll
    for (int i = 0; i < CH; i++) {
        int idx = base + i;
        uint32_t c = (idx < N_TYPE) ? total[idx] : 0u;
        local[i] = c;
        tsum += c;
    }
    uint32_t orig = tsum;
#pragma unroll
    for (int off = 1; off < 64; off <<= 1) {
        uint32_t v = __shfl_up(tsum, off, 64);
        if (lane >= off) tsum += v;
    }
    __shared__ uint32_t wsum[16];
    if (lane == 63) wsum[wv] = tsum;
    __syncthreads();
    if (wv == 0 && lane < 16) {
        uint32_t u = wsum[lane], o = u;
#pragma unroll
        for (int off = 1; off < 16; off <<= 1) {
            uint32_t v = __shfl_up(u, off, 64);
            if (lane >= off) u += v;
        }
        wsum[lane] = u - o;   // exclusive wave prefix
    }
    __syncthreads();
    uint32_t run = wsum[wv] + tsum - orig;   // exclusive thread prefix
#pragma unroll
    for (int i = 0; i < CH; i++) {
        int idx = base + i;
        if (idx < N_TYPE) {
            offsets[idx] = run;
            run += local[i];
        } else if (idx == N_TYPE) {
            offsets[idx] = run;   // == NEDGE
        }
    }
}

// ---- fill: 256 blocks; uint4 cursor init; upfront edge loads; LDS-atomic scatter ----
__global__ __launch_bounds__(256) void fill_k(const int* __restrict__ src,
                                              const int* __restrict__ dst,
                                              const uint32_t* __restrict__ offsets,
                                              const uint32_t* __restrict__ base2,
                                              uint32_t* __restrict__ edge_src) {
    __shared__ uint32_t cur[N_TYPE];   // 40 KB
    int cb = blockIdx.x;               // [0, HB)
    int t  = threadIdx.x;
    const uint32_t* brow = base2 + (size_t)cb * N_TYPE;
#pragma unroll
    for (int i = 0; i < 10; i++) {     // 2500 uint4 covers 10000 bins
        int idx = i * 256 + t;
        if (idx < N_TYPE / 4) {
            uint4 o = ((const uint4*)offsets)[idx];
            uint4 b = ((const uint4*)brow)[idx];
            uint4 c; c.x = o.x + b.x; c.y = o.y + b.y; c.z = o.z + b.z; c.w = o.w + b.w;
            ((uint4*)cur)[idx] = c;
        }
    }
    __syncthreads();
    int e0 = cb * HCHUNK;
    int dv[10], sv[10];
#pragma unroll
    for (int k = 0; k < 10; k++) {      // all 20 loads upfront
        int i = k * 256 + t;
        int e = e0 + (i < HCHUNK ? i : HCHUNK - 1);
        dv[k] = dst[e];
        sv[k] = src[e];
    }
    __builtin_amdgcn_sched_barrier(0);
#pragma unroll
    for (int k = 0; k < 10; k++) {
        int i = k * 256 + t;
        if (i < HCHUNK) {
            uint32_t pos = atomicAdd(&cur[dv[k]], 1u);   // LDS-only atomic
            edge_src[pos] = (uint32_t)sv[k];
        }
    }
}

// ---- agg v3: one wave per destination; HALF-WAVE row fetch (2 edges per load instr) ----
// 32 lanes x uint2 (8B) cover one 256B bf16 row; lanes 0-31 take even edges, 32-63 odd.
// 16-deep unroll => 32 edges (8 KB) in flight per wave (was 16 edges / 4 KB).
// Final shfl_xor(32) merges the half-accumulators; lanes 0-31 write uint2.
__global__ __launch_bounds__(256) void agg_k(const void* __restrict__ h_sent,
                                             const void* __restrict__ h_type,
                                             const float* __restrict__ s_src,
                                             const float* __restrict__ s_dst,
                                             const uint32_t* __restrict__ offsets,
                                             const uint32_t* __restrict__ edge_src,
                                             void* __restrict__ out) {
    __shared__ float    sc[4][MAXDEG];
    __shared__ uint32_t ss[4][MAXDEG];
    int j     = (blockIdx.x * 256 + threadIdx.x) >> 6;
    int wslot = threadIdx.x >> 6;
    int lane  = threadIdx.x & 63;
    int half  = lane >> 5;               // which edge of the pair this lane serves
    int hl    = lane & 31;               // dim-chunk index within the row
    bool valid = j < N_TYPE;
    bool isbf  = detect_bf16((const uint32_t*)h_sent);
    uint32_t beg = 0, deg = 0;
    float sdj = 0.0f;
    if (valid) {
        beg = offsets[j];
        deg = offsets[j + 1] - beg;
        sdj = s_dst[j];
    }
    float*    mysc = sc[wslot];
    uint32_t* myss = ss[wslot];
    bool fits = (deg <= MAXDEG);
    float m = -INFINITY;
    for (uint32_t k = lane; k < deg; k += 64) {
        uint32_t s = edge_src[beg + k];
        float v = s_src[s] + sdj;
        v = v > 0.0f ? v : 0.01f * v;
        if (fits) { mysc[k] = v; myss[k] = s; }
        m = fmaxf(m, v);
    }
#pragma unroll
    for (int off = 32; off; off >>= 1) m = fmaxf(m, __shfl_xor(m, off, 64));
    __syncthreads();   // LDS visibility (uniform: every thread reaches this)
    if (!valid) return;
    if (deg == 0) {    // isolated node keeps its input feature
        if (isbf) ((uint32_t*)out)[(size_t)j * 64 + lane] =
                      ((const uint32_t*)h_type)[(size_t)j * 64 + lane];
        else      ((float2*)out)[(size_t)j * 64 + lane] =
                      ((const float2*)h_type)[(size_t)j * 64 + lane];
        return;
    }
    float denom = 0.0f, a0 = 0.0f, a1 = 0.0f, a2 = 0.0f, a3 = 0.0f;
    if (isbf) {
        const uint2* hp = (const uint2*)h_sent;        // row stride = 32 uint2
        if (fits) {
            for (uint32_t k = 0; k < deg; k += 32) {   // 32 edges per iter, 16 loads
                uint32_t sv[16]; float vv[16]; uint2 gv[16];
#pragma unroll
                for (int i = 0; i < 16; i++) {
                    uint32_t e = k + 2u * i + (uint32_t)half;
                    bool ok = e < deg;
                    uint32_t ec = ok ? e : 0u;
                    sv[i] = myss[ec];
                    vv[i] = ok ? mysc[ec] : -INFINITY; // exp -> 0 contribution
                }
#pragma unroll
                for (int i = 0; i < 16; i++) gv[i] = hp[(size_t)sv[i] * 32 + hl];
#pragma unroll
                for (int i = 0; i < 16; i++) {
                    float w = __expf(vv[i] - m);
                    denom += w;
                    a0 += w * bf2f(gv[i].x & 0xffffu);
                    a1 += w * bf2f(gv[i].x >> 16);
                    a2 += w * bf2f(gv[i].y & 0xffffu);
                    a3 += w * bf2f(gv[i].y >> 16);
                }
            }
        } else {
            for (uint32_t k = 0; k < deg; k += 32) {
                uint32_t sv[16]; float vv[16]; uint2 gv[16];
#pragma unroll
                for (int i = 0; i < 16; i++) {
                    uint32_t e = k + 2u * i + (uint32_t)half;
                    bool ok = e < deg;
                    uint32_t ec = ok ? e : 0u;
                    uint32_t s = edge_src[beg + ec];
                    float v = s_src[s] + sdj; v = v > 0.0f ? v : 0.01f * v;
                    sv[i] = s;
                    vv[i] = ok ? v : -INFINITY;
                }
#pragma unroll
                for (int i = 0; i < 16; i++) gv[i] = hp[(size_t)sv[i] * 32 + hl];
#pragma unroll
                for (int i = 0; i < 16; i++) {
                    float w = __expf(vv[i] - m);
                    denom += w;
                    a0 += w * bf2f(gv[i].x & 0xffffu);
                    a1 += w * bf2f(gv[i].x >> 16);
                    a2 += w * bf2f(gv[i].y & 0xffffu);
                    a3 += w * bf2f(gv[i].y >> 16);
                }
            }
        }
        denom += __shfl_xor(denom, 32, 64);
        a0 += __shfl_xor(a0, 32, 64);
        a1 += __shfl_xor(a1, 32, 64);
        a2 += __shfl_xor(a2, 32, 64);
        a3 += __shfl_xor(a3, 32, 64);
        float inv = 1.0f / denom;
        if (half == 0) {
            uint2 o;
            o.x = f2bf(a0 * inv) | (f2bf(a1 * inv) << 16);
            o.y = f2bf(a2 * inv) | (f2bf(a3 * inv) << 16);
            ((uint2*)out)[(size_t)j * 32 + hl] = o;
        }
    } else {
        const float4* hp = (const float4*)h_sent;      // row stride = 32 float4
        if (fits) {
            for (uint32_t k = 0; k < deg; k += 16) {   // 16 edges per iter, 8 loads
                uint32_t sv[8]; float vv[8]; float4 gv[8];
#pragma unroll
                for (int i = 0; i < 8; i++) {
                    uint32_t e = k + 2u * i + (uint32_t)half;
                    bool ok = e < deg;
                    uint32_t ec = ok ? e : 0u;
                    sv[i] = myss[ec];
                    vv[i] = ok ? mysc[ec] : -INFINITY;
                }
#pragma unroll
                for (int i = 0; i < 8; i++) gv[i] = hp[(size_t)sv[i] * 32 + hl];
#pragma unroll
                for (int i = 0; i < 8; i++) {
                    float w = __expf(vv[i] - m);
                    denom += w;
                    a0 += w * gv[i].x;
                    a1 += w * gv[i].y;
                    a2 += w * gv[i].z;
                    a3 += w * gv[i].w;
                }
            }
        } else {
            for (uint32_t k = 0; k < deg; k += 16) {
                uint32_t sv[8]; float vv[8]; float4 gv[8];
#pragma unroll
                for (int i = 0; i < 8; i++) {
                    uint32_t e = k + 2u * i + (uint32_t)half;
                    bool ok = e < deg;
                    uint32_t ec = ok ? e : 0u;
                    uint32_t s = edge_src[beg + ec];
                    float v = s_src[s] + sdj; v = v > 0.0f ? v : 0.01f * v;
                    sv[i] = s;
                    vv[i] = ok ? v : -INFINITY;
                }
#pragma unroll
                for (int i = 0; i < 8; i++) gv[i] = hp[(size_t)sv[i] * 32 + hl];
#pragma unroll
                for (int i = 0; i < 8; i++) {
                    float w = __expf(vv[i] - m);
                    denom += w;
                    a0 += w * gv[i].x;
                    a1 += w * gv[i].y;
                    a2 += w * gv[i].z;
                    a3 += w * gv[i].w;
                }
            }
        }
        denom += __shfl_xor(denom, 32, 64);
        a0 += __shfl_xor(a0, 32, 64);
        a1 += __shfl_xor(a1, 32, 64);
        a2 += __shfl_xor(a2, 32, 64);
        a3 += __shfl_xor(a3, 32, 64);
        float inv = 1.0f / denom;
        if (half == 0) {
            float4 o = make_float4(a0 * inv, a1 * inv, a2 * inv, a3 * inv);
            ((float4*)out)[(size_t)j * 32 + hl] = o;
        }
    }
}

static inline size_t align_up(size_t x) { return (x + 255) & ~(size_t)255; }

extern "C" void kernel_launch(void* const* d_in, const int* in_sizes, int n_in,
                              void* d_out, int out_size, void* d_ws, size_t ws_size,
                              hipStream_t stream) {
    const void* h_sent = d_in[0];
    const void* h_type = d_in[1];
    const void* attn_w = d_in[2];
    const int* src_idx = (const int*)d_in[3];
    const int* dst_idx = (const int*)d_in[4];

    char* w = (char*)d_ws;
    float*    s_src     = (float*)w;    w += align_up((size_t)N_SENT * 4);
    float*    s_dst     = (float*)w;    w += align_up((size_t)N_TYPE * 4);
    uint32_t* count2    = (uint32_t*)w; w += align_up((size_t)HB * N_TYPE * 4);  // 10.24 MB
    uint32_t* total     = (uint32_t*)w; w += align_up((size_t)N_TYPE * 4);
    uint32_t* offsets   = (uint32_t*)w; w += align_up((size_t)(N_TYPE + 1) * 4);
    uint32_t* edge_src  = (uint32_t*)w; w += align_up((size_t)NEDGE * 4);
    // total ~13.4 MB

    scores_k<<<SC_BLOCKS, 256, 0, stream>>>(h_sent, h_type, attn_w, s_src, s_dst);
    count_k<<<HB, 256, 0, stream>>>(dst_idx, count2);
    sumscan_k<<<(N_TYPE * 8 + 255) / 256, 256, 0, stream>>>(count2, total);
    scan_k<<<1, 1024, 0, stream>>>(total, offsets);
    fill_k<<<HB, 256, 0, stream>>>(src_idx, dst_idx, offsets, count2, edge_src);
    agg_k<<<(N_TYPE + 3) / 4, 256, 0, stream>>>(h_sent, h_type, s_src, s_dst,
                                                offsets, edge_src, d_out);
}